// Round 2
// baseline (3484.901 us; speedup 1.0000x reference)
//
#include <hip/hip_runtime.h>

#define N_NODES 100000
#define N_EDGES 3200000
#define N_FEAT  128
#define DIM     48
#define N_CLASS 18
#define BN_EPS  1e-5f

#define PADK 132   // pad for K=128 tiles: row stride 528B
#define PADD 52    // pad for K=48 tiles: row stride 208B

// ---------------- edge preprocessing: counting sort by dst ----------------
// edge_index arrives as int32 per harness contract ("integer -> const int*")

__global__ __launch_bounds__(256) void k_hist(const int* __restrict__ ei,
                                              int* __restrict__ cnt) {
    int e = blockIdx.x * 256 + threadIdx.x;
    if (e < N_EDGES) {
        int d = ei[N_EDGES + e];
        atomicAdd(&cnt[d], 1);
    }
}

__global__ __launch_bounds__(1024) void k_scan(int* __restrict__ cnt /* becomes row_ptr */,
                                               int* __restrict__ cursor) {
    __shared__ int part[1024];
    const int t = threadIdx.x;
    const int CH = (N_NODES + 1023) / 1024;  // 98
    int begin = t * CH;
    int end = begin + CH; if (end > N_NODES) end = N_NODES;
    int sum = 0;
    for (int i = begin; i < end; i++) sum += cnt[i];
    part[t] = sum;
    __syncthreads();
    // inclusive Hillis-Steele scan over 1024 partials
    for (int off = 1; off < 1024; off <<= 1) {
        int v = (t >= off) ? part[t - off] : 0;
        __syncthreads();
        part[t] += v;
        __syncthreads();
    }
    int run = (t == 0) ? 0 : part[t - 1];
    for (int i = begin; i < end; i++) {
        int c = cnt[i];
        cnt[i] = run;       // exclusive prefix -> row_ptr[i]
        cursor[i] = run;
        run += c;
    }
    if (t == 1023) cnt[N_NODES] = part[1023];  // row_ptr[N] = total edges
}

__global__ __launch_bounds__(256) void k_scatter(const int* __restrict__ ei,
                                                 int* __restrict__ cursor,
                                                 int* __restrict__ sorted_src) {
    int e = blockIdx.x * 256 + threadIdx.x;
    if (e < N_EDGES) {
        int d = ei[N_EDGES + e];
        int s = ei[e];
        int pos = atomicAdd(&cursor[d], 1);
        sorted_src[pos] = s;
    }
}

// ---------------- conv1 front: t1 = x@W1, t2 = relu(x)@W1 ----------------

__global__ __launch_bounds__(256) void k_g1(const float* __restrict__ x,
                                            const float* __restrict__ W1,
                                            float* __restrict__ t1,
                                            float* __restrict__ t2) {
    __shared__ float sX[64 * PADK];
    __shared__ float sW[DIM * PADK];   // W1 transposed: [col][k]
    const int t = threadIdx.x;
    const int base = blockIdx.x * 64;

    for (int idx = t; idx < N_FEAT * DIM; idx += 256) {
        int k = idx / DIM, c = idx - k * DIM;
        sW[c * PADK + k] = W1[idx];
    }
    for (int idx = t; idx < 64 * 32; idx += 256) {
        int row = idx >> 5, kq = idx & 31;
        float4 v = make_float4(0.f, 0.f, 0.f, 0.f);
        if (base + row < N_NODES) v = ((const float4*)x)[(base + row) * 32 + kq];
        *(float4*)&sX[row * PADK + kq * 4] = v;
    }
    __syncthreads();

    const int col = t & 63, rg = t >> 6;
    if (col < DIM) {
        float acc1[16], acc2[16];
        #pragma unroll
        for (int i = 0; i < 16; i++) { acc1[i] = 0.f; acc2[i] = 0.f; }
        #pragma unroll
        for (int a = 0; a < 4; a++) {
            #pragma unroll
            for (int kq = 0; kq < 32; kq++) {
                float4 w = *(const float4*)&sW[col * PADK + kq * 4];
                #pragma unroll
                for (int j = 0; j < 4; j++) {
                    int row = rg + 16 * a + 4 * j;
                    float4 xv = *(const float4*)&sX[row * PADK + kq * 4];
                    acc1[4 * a + j] += xv.x * w.x + xv.y * w.y + xv.z * w.z + xv.w * w.w;
                    acc2[4 * a + j] += fmaxf(xv.x, 0.f) * w.x + fmaxf(xv.y, 0.f) * w.y
                                     + fmaxf(xv.z, 0.f) * w.z + fmaxf(xv.w, 0.f) * w.w;
                }
            }
        }
        #pragma unroll
        for (int i = 0; i < 16; i++) {
            int gr = base + rg + 4 * i;
            if (gr < N_NODES) {
                t1[gr * DIM + col] = acc1[i];
                t2[gr * DIM + col] = acc2[i];
            }
        }
    }
}

// ---------------- aggregation: out = relu(tlin + segsum(tmsg) + bias) ----------------
// NOTE: out aliases tlin (same buffer). Each thread reads tlin[n] before
// writing out[n]; no other thread touches row n. No __restrict__ on these two.

__global__ __launch_bounds__(256) void k_aggr(const float* tlin,
                                              const float* __restrict__ tmsg,
                                              const int* __restrict__ row_ptr,
                                              const int* __restrict__ ssrc,
                                              const float* __restrict__ bias,
                                              float* out) {
    int n = blockIdx.x * 4 + (threadIdx.x >> 6);
    int lane = threadIdx.x & 63;
    if (n >= N_NODES) return;
    int start = row_ptr[n], end = row_ptr[n + 1];
    bool act = lane < DIM;
    float acc = 0.f;
    int e = start;
    for (; e + 4 <= end; e += 4) {
        int s0 = ssrc[e], s1 = ssrc[e + 1], s2 = ssrc[e + 2], s3 = ssrc[e + 3];
        if (act) {
            float v0 = tmsg[s0 * DIM + lane];
            float v1 = tmsg[s1 * DIM + lane];
            float v2 = tmsg[s2 * DIM + lane];
            float v3 = tmsg[s3 * DIM + lane];
            acc += (v0 + v1) + (v2 + v3);
        }
    }
    for (; e < end; e++) {
        int s = ssrc[e];
        if (act) acc += tmsg[s * DIM + lane];
    }
    if (act) {
        float base = tlin[n * DIM + lane];   // read BEFORE aliased write
        float v = base + acc + bias[lane];
        out[n * DIM + lane] = fmaxf(v, 0.f);
    }
}

// ---------------- chain1: v=u@c1W2+b2; g1=bn1(relu(v)); t3=g1@c2W1; t4=relu(g1)@c2W1 ----------------
// NOTE: t3 aliases u (same buffer). The u-tile is fully staged into LDS before
// the first __syncthreads(); t3 writes happen after; rows are block-exclusive.

__global__ __launch_bounds__(256) void k_chain1(const float* u,
                                                const float* __restrict__ W2,
                                                const float* __restrict__ b2,
                                                const float* __restrict__ bng,
                                                const float* __restrict__ bnb,
                                                const float* __restrict__ bnm,
                                                const float* __restrict__ bnv,
                                                const float* __restrict__ W1n,
                                                float* t3,
                                                float* __restrict__ t4) {
    __shared__ float sU[64 * PADD];
    __shared__ float sW2[DIM * PADD];
    __shared__ float sW1[DIM * PADD];
    __shared__ float sG[64 * PADD];
    const int t = threadIdx.x;
    const int base = blockIdx.x * 64;

    for (int idx = t; idx < DIM * DIM; idx += 256) {
        int k = idx / DIM, c = idx - k * DIM;
        sW2[c * PADD + k] = W2[idx];
        sW1[c * PADD + k] = W1n[idx];
    }
    for (int idx = t; idx < 64 * 12; idx += 256) {
        int row = idx / 12, kq = idx - row * 12;
        float4 v = make_float4(0.f, 0.f, 0.f, 0.f);
        if (base + row < N_NODES) v = ((const float4*)u)[(base + row) * 12 + kq];
        *(float4*)&sU[row * PADD + kq * 4] = v;
    }
    const int col = t & 63, rg = t >> 6;
    float bias2 = 0.f, sc = 0.f, sh = 0.f;
    if (col < DIM) {
        bias2 = b2[col];
        sc = bng[col] * rsqrtf(bnv[col] + BN_EPS);
        sh = bnb[col] - bnm[col] * sc;
    }
    __syncthreads();

    if (col < DIM) {
        float acc[16];
        #pragma unroll
        for (int i = 0; i < 16; i++) acc[i] = 0.f;
        #pragma unroll
        for (int a = 0; a < 4; a++) {
            #pragma unroll
            for (int kq = 0; kq < 12; kq++) {
                float4 w = *(const float4*)&sW2[col * PADD + kq * 4];
                #pragma unroll
                for (int j = 0; j < 4; j++) {
                    int row = rg + 16 * a + 4 * j;
                    float4 xv = *(const float4*)&sU[row * PADD + kq * 4];
                    acc[4 * a + j] += xv.x * w.x + xv.y * w.y + xv.z * w.z + xv.w * w.w;
                }
            }
        }
        #pragma unroll
        for (int i = 0; i < 16; i++) {
            float v = acc[i] + bias2;
            float r = fmaxf(v, 0.f);
            sG[(rg + 4 * i) * PADD + col] = r * sc + sh;
        }
    }
    __syncthreads();

    if (col < DIM) {
        float a3[16], a4[16];
        #pragma unroll
        for (int i = 0; i < 16; i++) { a3[i] = 0.f; a4[i] = 0.f; }
        #pragma unroll
        for (int a = 0; a < 4; a++) {
            #pragma unroll
            for (int kq = 0; kq < 12; kq++) {
                float4 w = *(const float4*)&sW1[col * PADD + kq * 4];
                #pragma unroll
                for (int j = 0; j < 4; j++) {
                    int row = rg + 16 * a + 4 * j;
                    float4 g = *(const float4*)&sG[row * PADD + kq * 4];
                    a3[4 * a + j] += g.x * w.x + g.y * w.y + g.z * w.z + g.w * w.w;
                    a4[4 * a + j] += fmaxf(g.x, 0.f) * w.x + fmaxf(g.y, 0.f) * w.y
                                   + fmaxf(g.z, 0.f) * w.z + fmaxf(g.w, 0.f) * w.w;
                }
            }
        }
        #pragma unroll
        for (int i = 0; i < 16; i++) {
            int gr = base + rg + 4 * i;
            if (gr < N_NODES) {
                t3[gr * DIM + col] = a3[i];
                t4[gr * DIM + col] = a4[i];
            }
        }
    }
}

// ---------------- chain2: v2=u2@c2W2+b2; g2=bn2(relu); z=relu(g2@fc1+b); out=z@fc2+b ----------------

__global__ __launch_bounds__(256) void k_chain2(const float* __restrict__ u2,
                                                const float* __restrict__ W2,
                                                const float* __restrict__ b2,
                                                const float* __restrict__ bng,
                                                const float* __restrict__ bnb,
                                                const float* __restrict__ bnm,
                                                const float* __restrict__ bnv,
                                                const float* __restrict__ fc1W,
                                                const float* __restrict__ fc1b,
                                                const float* __restrict__ fc2W,
                                                const float* __restrict__ fc2b,
                                                float* __restrict__ out) {
    __shared__ float sA[64 * PADD];
    __shared__ float sB[64 * PADD];
    __shared__ float sWa[DIM * PADD];
    __shared__ float sWb[DIM * PADD];
    __shared__ float sWc[N_CLASS * PADD];
    const int t = threadIdx.x;
    const int base = blockIdx.x * 64;

    for (int idx = t; idx < DIM * DIM; idx += 256) {
        int k = idx / DIM, c = idx - k * DIM;
        sWa[c * PADD + k] = W2[idx];
        sWb[c * PADD + k] = fc1W[idx];
    }
    for (int idx = t; idx < DIM * N_CLASS; idx += 256) {
        int k = idx / N_CLASS, c = idx - k * N_CLASS;
        sWc[c * PADD + k] = fc2W[idx];
    }
    for (int idx = t; idx < 64 * 12; idx += 256) {
        int row = idx / 12, kq = idx - row * 12;
        float4 v = make_float4(0.f, 0.f, 0.f, 0.f);
        if (base + row < N_NODES) v = ((const float4*)u2)[(base + row) * 12 + kq];
        *(float4*)&sA[row * PADD + kq * 4] = v;
    }
    const int col = t & 63, rg = t >> 6;
    float bias2 = 0.f, sc = 0.f, sh = 0.f, b1 = 0.f, bC = 0.f;
    if (col < DIM) {
        bias2 = b2[col];
        sc = bng[col] * rsqrtf(bnv[col] + BN_EPS);
        sh = bnb[col] - bnm[col] * sc;
        b1 = fc1b[col];
    }
    if (col < N_CLASS) bC = fc2b[col];
    __syncthreads();

    // phase 1: g2 = bn2(relu(u2@W2 + b2)) -> sB
    if (col < DIM) {
        float acc[16];
        #pragma unroll
        for (int i = 0; i < 16; i++) acc[i] = 0.f;
        #pragma unroll
        for (int a = 0; a < 4; a++) {
            #pragma unroll
            for (int kq = 0; kq < 12; kq++) {
                float4 w = *(const float4*)&sWa[col * PADD + kq * 4];
                #pragma unroll
                for (int j = 0; j < 4; j++) {
                    int row = rg + 16 * a + 4 * j;
                    float4 xv = *(const float4*)&sA[row * PADD + kq * 4];
                    acc[4 * a + j] += xv.x * w.x + xv.y * w.y + xv.z * w.z + xv.w * w.w;
                }
            }
        }
        #pragma unroll
        for (int i = 0; i < 16; i++) {
            float r = fmaxf(acc[i] + bias2, 0.f);
            sB[(rg + 4 * i) * PADD + col] = r * sc + sh;
        }
    }
    __syncthreads();

    // phase 2: z = relu(g2@fc1W + fc1b) -> sA (u2 tile fully consumed)
    if (col < DIM) {
        float acc[16];
        #pragma unroll
        for (int i = 0; i < 16; i++) acc[i] = 0.f;
        #pragma unroll
        for (int a = 0; a < 4; a++) {
            #pragma unroll
            for (int kq = 0; kq < 12; kq++) {
                float4 w = *(const float4*)&sWb[col * PADD + kq * 4];
                #pragma unroll
                for (int j = 0; j < 4; j++) {
                    int row = rg + 16 * a + 4 * j;
                    float4 g = *(const float4*)&sB[row * PADD + kq * 4];
                    acc[4 * a + j] += g.x * w.x + g.y * w.y + g.z * w.z + g.w * w.w;
                }
            }
        }
        __syncthreads();
        #pragma unroll
        for (int i = 0; i < 16; i++)
            sA[(rg + 4 * i) * PADD + col] = fmaxf(acc[i] + b1, 0.f);
    } else {
        __syncthreads();
    }
    __syncthreads();

    // phase 3: out = z@fc2W + fc2b
    if (col < N_CLASS) {
        float acc[16];
        #pragma unroll
        for (int i = 0; i < 16; i++) acc[i] = 0.f;
        #pragma unroll
        for (int a = 0; a < 4; a++) {
            #pragma unroll
            for (int kq = 0; kq < 12; kq++) {
                float4 w = *(const float4*)&sWc[col * PADD + kq * 4];
                #pragma unroll
                for (int j = 0; j < 4; j++) {
                    int row = rg + 16 * a + 4 * j;
                    float4 z = *(const float4*)&sA[row * PADD + kq * 4];
                    acc[4 * a + j] += z.x * w.x + z.y * w.y + z.z * w.z + z.w * w.w;
                }
            }
        }
        #pragma unroll
        for (int i = 0; i < 16; i++) {
            int gr = base + rg + 4 * i;
            if (gr < N_NODES) out[gr * N_CLASS + col] = acc[i] + bC;
        }
    }
}

// ---------------- launch ----------------

extern "C" void kernel_launch(void* const* d_in, const int* in_sizes, int n_in,
                              void* d_out, int out_size, void* d_ws, size_t ws_size,
                              hipStream_t stream) {
    const float* x     = (const float*)d_in[0];
    const int*   ei    = (const int*)d_in[1];   // int32 per harness contract
    const float* c1_W1 = (const float*)d_in[2];
    const float* c1_b1 = (const float*)d_in[3];
    const float* c1_W2 = (const float*)d_in[4];
    const float* c1_b2 = (const float*)d_in[5];
    const float* c2_W1 = (const float*)d_in[6];
    const float* c2_b1 = (const float*)d_in[7];
    const float* c2_W2 = (const float*)d_in[8];
    const float* c2_b2 = (const float*)d_in[9];
    const float* bn1_g = (const float*)d_in[10];
    const float* bn1_b = (const float*)d_in[11];
    const float* bn1_m = (const float*)d_in[12];
    const float* bn1_v = (const float*)d_in[13];
    const float* bn2_g = (const float*)d_in[14];
    const float* bn2_b = (const float*)d_in[15];
    const float* bn2_m = (const float*)d_in[16];
    const float* bn2_v = (const float*)d_in[17];
    const float* fc1_W = (const float*)d_in[18];
    const float* fc1_b = (const float*)d_in[19];
    const float* fc2_W = (const float*)d_in[20];
    const float* fc2_b = (const float*)d_in[21];
    float* out = (float*)d_out;

    // workspace layout (256B-aligned chunks), ~52 MB total
    char* ws = (char*)d_ws;
    size_t o = 0;
    auto take = [&](size_t bytes) {
        void* p = ws + o;
        o = (o + bytes + 255) & ~(size_t)255;
        return p;
    };
    int*   sorted_src = (int*)take((size_t)N_EDGES * 4);
    int*   row_ptr    = (int*)take((size_t)(N_NODES + 1) * 4);
    int*   cursor     = (int*)take((size_t)N_NODES * 4);
    float* t1         = (float*)take((size_t)N_NODES * DIM * 4);  // aliased: t1 / u / t3 / u2
    float* t2         = (float*)take((size_t)N_NODES * DIM * 4);  // t2 / t4
    (void)ws_size; (void)in_sizes; (void)n_in; (void)out_size;

    const int EB = N_EDGES / 256;           // 12500 exact
    const int NB64 = (N_NODES + 63) / 64;   // 1563
    const int NB4  = (N_NODES + 3) / 4;     // 25000 exact

    hipMemsetAsync(row_ptr, 0, (size_t)(N_NODES + 1) * 4, stream);
    k_hist<<<EB, 256, 0, stream>>>(ei, row_ptr);
    k_scan<<<1, 1024, 0, stream>>>(row_ptr, cursor);
    k_scatter<<<EB, 256, 0, stream>>>(ei, cursor, sorted_src);

    k_g1<<<NB64, 256, 0, stream>>>(x, c1_W1, t1, t2);
    k_aggr<<<NB4, 256, 0, stream>>>(t1, t2, row_ptr, sorted_src, c1_b1, t1);
    k_chain1<<<NB64, 256, 0, stream>>>(t1, c1_W2, c1_b2, bn1_g, bn1_b, bn1_m, bn1_v,
                                       c2_W1, t1, t2);
    k_aggr<<<NB4, 256, 0, stream>>>(t1, t2, row_ptr, sorted_src, c2_b1, t1);
    k_chain2<<<NB64, 256, 0, stream>>>(t1, c2_W2, c2_b2, bn2_g, bn2_b, bn2_m, bn2_v,
                                       fc1_W, fc1_b, fc2_W, fc2_b, out);
}

// Round 3
// 991.550 us; speedup vs baseline: 3.5146x; 3.5146x over previous
//
#include <hip/hip_runtime.h>

#define N_NODES 100000
#define N_EDGES 3200000
#define N_FEAT  128
#define DIM     48
#define N_CLASS 18
#define BN_EPS  1e-5f

#define PADK 132   // x-tile row stride (dwords); 132%32=4 -> 2-way bank alias (free)
#define PADD 52    // 48-wide tile row stride; 52%32=20 -> 2-way bank alias (free)

// ---------------- edge preprocessing: counting sort by dst ----------------

__global__ __launch_bounds__(256) void k_hist(const int* __restrict__ ei,
                                              int* __restrict__ cnt) {
    int e = blockIdx.x * 256 + threadIdx.x;
    if (e < N_EDGES) {
        int d = ei[N_EDGES + e];
        atomicAdd(&cnt[d], 1);
    }
}

__global__ __launch_bounds__(1024) void k_scan(int* __restrict__ cnt /* becomes row_ptr */,
                                               int* __restrict__ cursor) {
    __shared__ int part[1024];
    const int t = threadIdx.x;
    const int CH = (N_NODES + 1023) / 1024;  // 98
    int begin = t * CH;
    int end = begin + CH; if (end > N_NODES) end = N_NODES;
    int sum = 0;
    for (int i = begin; i < end; i++) sum += cnt[i];
    part[t] = sum;
    __syncthreads();
    for (int off = 1; off < 1024; off <<= 1) {
        int v = (t >= off) ? part[t - off] : 0;
        __syncthreads();
        part[t] += v;
        __syncthreads();
    }
    int run = (t == 0) ? 0 : part[t - 1];
    for (int i = begin; i < end; i++) {
        int c = cnt[i];
        cnt[i] = run;
        cursor[i] = run;
        run += c;
    }
    if (t == 1023) cnt[N_NODES] = part[1023];
}

__global__ __launch_bounds__(256) void k_scatter(const int* __restrict__ ei,
                                                 int* __restrict__ cursor,
                                                 int* __restrict__ sorted_src) {
    int e = blockIdx.x * 256 + threadIdx.x;
    if (e < N_EDGES) {
        int d = ei[N_EDGES + e];
        int s = ei[e];
        int pos = atomicAdd(&cursor[d], 1);
        sorted_src[pos] = s;
    }
}

// ---------------- conv1 front: t1 = x@W1, t2 = relu(x)@W1 ----------------
// 64 rows/block; per thread: 2 rows x 6 cols, dual accumulators (24 regs).

__global__ __launch_bounds__(256) void k_g1(const float* __restrict__ x,
                                            const float* __restrict__ W1,
                                            float* __restrict__ t1,
                                            float* __restrict__ t2) {
    __shared__ float sX[64 * PADK];
    __shared__ float sW[DIM * PADK];   // W1^T: [col][k]
    const int t = threadIdx.x;
    const int base = blockIdx.x * 64;

    for (int idx = t; idx < N_FEAT * DIM; idx += 256) {
        int k = idx / DIM, c = idx - k * DIM;
        sW[c * PADK + k] = W1[idx];
    }
    for (int idx = t; idx < 64 * 32; idx += 256) {
        int row = idx >> 5, kq = idx & 31;
        float4 v = make_float4(0.f, 0.f, 0.f, 0.f);
        if (base + row < N_NODES) v = ((const float4*)x)[(base + row) * 32 + kq];
        *(float4*)&sX[row * PADK + kq * 4] = v;
    }
    __syncthreads();

    const int cg = t & 7;          // cols cg*6 .. cg*6+5
    const int rg = t >> 3;         // rows rg*2, rg*2+1
    const int r0 = rg * 2;
    const int c0 = cg * 6;

    float a1[2][6], a2[2][6];
    #pragma unroll
    for (int r = 0; r < 2; r++)
        #pragma unroll
        for (int c = 0; c < 6; c++) { a1[r][c] = 0.f; a2[r][c] = 0.f; }

    #pragma unroll 2
    for (int kq = 0; kq < 32; kq++) {
        float4 x0 = *(const float4*)&sX[(r0 + 0) * PADK + kq * 4];
        float4 x1 = *(const float4*)&sX[(r0 + 1) * PADK + kq * 4];
        float4 p0 = make_float4(fmaxf(x0.x, 0.f), fmaxf(x0.y, 0.f), fmaxf(x0.z, 0.f), fmaxf(x0.w, 0.f));
        float4 p1 = make_float4(fmaxf(x1.x, 0.f), fmaxf(x1.y, 0.f), fmaxf(x1.z, 0.f), fmaxf(x1.w, 0.f));
        #pragma unroll
        for (int c = 0; c < 6; c++) {
            float4 w = *(const float4*)&sW[(c0 + c) * PADK + kq * 4];
            a1[0][c] += x0.x * w.x + x0.y * w.y + x0.z * w.z + x0.w * w.w;
            a1[1][c] += x1.x * w.x + x1.y * w.y + x1.z * w.z + x1.w * w.w;
            a2[0][c] += p0.x * w.x + p0.y * w.y + p0.z * w.z + p0.w * w.w;
            a2[1][c] += p1.x * w.x + p1.y * w.y + p1.z * w.z + p1.w * w.w;
        }
    }

    #pragma unroll
    for (int r = 0; r < 2; r++) {
        int gr = base + r0 + r;
        if (gr < N_NODES) {
            #pragma unroll
            for (int c = 0; c < 3; c++) {   // float2 stores (8B aligned: gr*48+c0 even)
                *(float2*)&t1[gr * DIM + c0 + 2 * c] = make_float2(a1[r][2 * c], a1[r][2 * c + 1]);
                *(float2*)&t2[gr * DIM + c0 + 2 * c] = make_float2(a2[r][2 * c], a2[r][2 * c + 1]);
            }
        }
    }
}

// ---------------- aggregation: out = relu(tlin + segsum(tmsg) + bias) ----------------
// out aliases tlin: each thread reads tlin[n,lane] before writing; row-exclusive.

__global__ __launch_bounds__(256) void k_aggr(const float* tlin,
                                              const float* __restrict__ tmsg,
                                              const int* __restrict__ row_ptr,
                                              const int* __restrict__ ssrc,
                                              const float* __restrict__ bias,
                                              float* out) {
    int n = blockIdx.x * 4 + (threadIdx.x >> 6);
    int lane = threadIdx.x & 63;
    if (n >= N_NODES) return;
    int start = row_ptr[n], end = row_ptr[n + 1];
    bool act = lane < DIM;
    float acc = 0.f;
    int e = start;
    for (; e + 4 <= end; e += 4) {
        int s0 = ssrc[e], s1 = ssrc[e + 1], s2 = ssrc[e + 2], s3 = ssrc[e + 3];
        if (act) {
            float v0 = tmsg[s0 * DIM + lane];
            float v1 = tmsg[s1 * DIM + lane];
            float v2 = tmsg[s2 * DIM + lane];
            float v3 = tmsg[s3 * DIM + lane];
            acc += (v0 + v1) + (v2 + v3);
        }
    }
    for (; e < end; e++) {
        int s = ssrc[e];
        if (act) acc += tmsg[s * DIM + lane];
    }
    if (act) {
        float base = tlin[n * DIM + lane];
        out[n * DIM + lane] = fmaxf(base + acc + bias[lane], 0.f);
    }
}

// ---------------- chain1: v=u@c1W2+b2; g1=bn1(relu(v)); t3=g1@c2W1; t4=relu(g1)@c2W1 ----------------
// t3 aliases u: u fully staged to LDS before first sync; writes after; row-exclusive.

__global__ __launch_bounds__(256) void k_chain1(const float* u,
                                                const float* __restrict__ W2,
                                                const float* __restrict__ b2,
                                                const float* __restrict__ bng,
                                                const float* __restrict__ bnb,
                                                const float* __restrict__ bnm,
                                                const float* __restrict__ bnv,
                                                const float* __restrict__ W1n,
                                                float* t3,
                                                float* __restrict__ t4) {
    __shared__ float sU[64 * PADD];
    __shared__ float sG[64 * PADD];
    __shared__ float sW2[DIM * PADD];
    __shared__ float sW1[DIM * PADD];
    const int t = threadIdx.x;
    const int base = blockIdx.x * 64;

    for (int idx = t; idx < DIM * DIM; idx += 256) {
        int k = idx / DIM, c = idx - k * DIM;
        sW2[c * PADD + k] = W2[idx];
        sW1[c * PADD + k] = W1n[idx];
    }
    for (int idx = t; idx < 64 * 12; idx += 256) {
        int row = idx / 12, kq = idx - row * 12;
        float4 v = make_float4(0.f, 0.f, 0.f, 0.f);
        if (base + row < N_NODES) v = ((const float4*)u)[(base + row) * 12 + kq];
        *(float4*)&sU[row * PADD + kq * 4] = v;
    }
    __syncthreads();

    const int cg = t & 7, rg = t >> 3;
    const int r0 = rg * 2, c0 = cg * 6;

    // GEMM1: g = bn1(relu(u@W2 + b2)) -> sG
    {
        float g[2][6];
        #pragma unroll
        for (int r = 0; r < 2; r++)
            #pragma unroll
            for (int c = 0; c < 6; c++) g[r][c] = 0.f;

        #pragma unroll 2
        for (int kq = 0; kq < 12; kq++) {
            float4 x0 = *(const float4*)&sU[(r0 + 0) * PADD + kq * 4];
            float4 x1 = *(const float4*)&sU[(r0 + 1) * PADD + kq * 4];
            #pragma unroll
            for (int c = 0; c < 6; c++) {
                float4 w = *(const float4*)&sW2[(c0 + c) * PADD + kq * 4];
                g[0][c] += x0.x * w.x + x0.y * w.y + x0.z * w.z + x0.w * w.w;
                g[1][c] += x1.x * w.x + x1.y * w.y + x1.z * w.z + x1.w * w.w;
            }
        }
        #pragma unroll
        for (int c = 0; c < 6; c++) {
            float bb = b2[c0 + c];
            float sc = bng[c0 + c] * rsqrtf(bnv[c0 + c] + BN_EPS);
            float sh = bnb[c0 + c] - bnm[c0 + c] * sc;
            #pragma unroll
            for (int r = 0; r < 2; r++) {
                float rl = fmaxf(g[r][c] + bb, 0.f);
                sG[(r0 + r) * PADD + c0 + c] = rl * sc + sh;
            }
        }
    }
    __syncthreads();

    // GEMM2 (dual): t3 = g@W1n, t4 = relu(g)@W1n
    {
        float a3[2][6], a4[2][6];
        #pragma unroll
        for (int r = 0; r < 2; r++)
            #pragma unroll
            for (int c = 0; c < 6; c++) { a3[r][c] = 0.f; a4[r][c] = 0.f; }

        #pragma unroll 2
        for (int kq = 0; kq < 12; kq++) {
            float4 x0 = *(const float4*)&sG[(r0 + 0) * PADD + kq * 4];
            float4 x1 = *(const float4*)&sG[(r0 + 1) * PADD + kq * 4];
            float4 p0 = make_float4(fmaxf(x0.x, 0.f), fmaxf(x0.y, 0.f), fmaxf(x0.z, 0.f), fmaxf(x0.w, 0.f));
            float4 p1 = make_float4(fmaxf(x1.x, 0.f), fmaxf(x1.y, 0.f), fmaxf(x1.z, 0.f), fmaxf(x1.w, 0.f));
            #pragma unroll
            for (int c = 0; c < 6; c++) {
                float4 w = *(const float4*)&sW1[(c0 + c) * PADD + kq * 4];
                a3[0][c] += x0.x * w.x + x0.y * w.y + x0.z * w.z + x0.w * w.w;
                a3[1][c] += x1.x * w.x + x1.y * w.y + x1.z * w.z + x1.w * w.w;
                a4[0][c] += p0.x * w.x + p0.y * w.y + p0.z * w.z + p0.w * w.w;
                a4[1][c] += p1.x * w.x + p1.y * w.y + p1.z * w.z + p1.w * w.w;
            }
        }
        #pragma unroll
        for (int r = 0; r < 2; r++) {
            int gr = base + r0 + r;
            if (gr < N_NODES) {
                #pragma unroll
                for (int c = 0; c < 3; c++) {
                    *(float2*)&t3[gr * DIM + c0 + 2 * c] = make_float2(a3[r][2 * c], a3[r][2 * c + 1]);
                    *(float2*)&t4[gr * DIM + c0 + 2 * c] = make_float2(a4[r][2 * c], a4[r][2 * c + 1]);
                }
            }
        }
    }
}

// ---------------- chain2: v2=u2@c2W2+b2; g2=bn2(relu); z=relu(g2@fc1+b); out=z@fc2+b ----------------

__global__ __launch_bounds__(256) void k_chain2(const float* __restrict__ u2,
                                                const float* __restrict__ W2,
                                                const float* __restrict__ b2,
                                                const float* __restrict__ bng,
                                                const float* __restrict__ bnb,
                                                const float* __restrict__ bnm,
                                                const float* __restrict__ bnv,
                                                const float* __restrict__ fc1W,
                                                const float* __restrict__ fc1b,
                                                const float* __restrict__ fc2W,
                                                const float* __restrict__ fc2b,
                                                float* __restrict__ out) {
    __shared__ float sA[64 * PADD];
    __shared__ float sB[64 * PADD];
    __shared__ float sWa[DIM * PADD];
    __shared__ float sWb[DIM * PADD];
    __shared__ float sWc[N_CLASS * PADD];
    const int t = threadIdx.x;
    const int base = blockIdx.x * 64;

    for (int idx = t; idx < DIM * DIM; idx += 256) {
        int k = idx / DIM, c = idx - k * DIM;
        sWa[c * PADD + k] = W2[idx];
        sWb[c * PADD + k] = fc1W[idx];
    }
    for (int idx = t; idx < DIM * N_CLASS; idx += 256) {
        int k = idx / N_CLASS, c = idx - k * N_CLASS;
        sWc[c * PADD + k] = fc2W[idx];
    }
    for (int idx = t; idx < 64 * 12; idx += 256) {
        int row = idx / 12, kq = idx - row * 12;
        float4 v = make_float4(0.f, 0.f, 0.f, 0.f);
        if (base + row < N_NODES) v = ((const float4*)u2)[(base + row) * 12 + kq];
        *(float4*)&sA[row * PADD + kq * 4] = v;
    }
    __syncthreads();

    const int cg = t & 7, rg = t >> 3;
    const int r0 = rg * 2, c0 = cg * 6;

    // P1: g2 = bn2(relu(u2@W2 + b2)) -> sB
    {
        float g[2][6];
        #pragma unroll
        for (int r = 0; r < 2; r++)
            #pragma unroll
            for (int c = 0; c < 6; c++) g[r][c] = 0.f;
        #pragma unroll 2
        for (int kq = 0; kq < 12; kq++) {
            float4 x0 = *(const float4*)&sA[(r0 + 0) * PADD + kq * 4];
            float4 x1 = *(const float4*)&sA[(r0 + 1) * PADD + kq * 4];
            #pragma unroll
            for (int c = 0; c < 6; c++) {
                float4 w = *(const float4*)&sWa[(c0 + c) * PADD + kq * 4];
                g[0][c] += x0.x * w.x + x0.y * w.y + x0.z * w.z + x0.w * w.w;
                g[1][c] += x1.x * w.x + x1.y * w.y + x1.z * w.z + x1.w * w.w;
            }
        }
        #pragma unroll
        for (int c = 0; c < 6; c++) {
            float bb = b2[c0 + c];
            float sc = bng[c0 + c] * rsqrtf(bnv[c0 + c] + BN_EPS);
            float sh = bnb[c0 + c] - bnm[c0 + c] * sc;
            #pragma unroll
            for (int r = 0; r < 2; r++) {
                float rl = fmaxf(g[r][c] + bb, 0.f);
                sB[(r0 + r) * PADD + c0 + c] = rl * sc + sh;
            }
        }
    }
    __syncthreads();

    // P2: z = relu(g2@fc1 + b1) -> sA (u2 tile fully consumed by P1)
    {
        float z[2][6];
        #pragma unroll
        for (int r = 0; r < 2; r++)
            #pragma unroll
            for (int c = 0; c < 6; c++) z[r][c] = 0.f;
        #pragma unroll 2
        for (int kq = 0; kq < 12; kq++) {
            float4 x0 = *(const float4*)&sB[(r0 + 0) * PADD + kq * 4];
            float4 x1 = *(const float4*)&sB[(r0 + 1) * PADD + kq * 4];
            #pragma unroll
            for (int c = 0; c < 6; c++) {
                float4 w = *(const float4*)&sWb[(c0 + c) * PADD + kq * 4];
                z[0][c] += x0.x * w.x + x0.y * w.y + x0.z * w.z + x0.w * w.w;
                z[1][c] += x1.x * w.x + x1.y * w.y + x1.z * w.z + x1.w * w.w;
            }
        }
        __syncthreads();   // everyone done reading sB? (sB not rewritten; this guards sA rewrite vs P1 readers)
        #pragma unroll
        for (int c = 0; c < 6; c++) {
            float bb = fc1b[c0 + c];
            #pragma unroll
            for (int r = 0; r < 2; r++)
                sA[(r0 + r) * PADD + c0 + c] = fmaxf(z[r][c] + bb, 0.f);
        }
    }
    __syncthreads();

    // P3: out = z@fc2 + b  (64 rows x 18 cols; cg<6 active, 3 cols each)
    if (cg < 6) {
        const int cc0 = cg * 3;
        float o[2][3];
        #pragma unroll
        for (int r = 0; r < 2; r++)
            #pragma unroll
            for (int c = 0; c < 3; c++) o[r][c] = 0.f;
        #pragma unroll 2
        for (int kq = 0; kq < 12; kq++) {
            float4 x0 = *(const float4*)&sA[(r0 + 0) * PADD + kq * 4];
            float4 x1 = *(const float4*)&sA[(r0 + 1) * PADD + kq * 4];
            #pragma unroll
            for (int c = 0; c < 3; c++) {
                float4 w = *(const float4*)&sWc[(cc0 + c) * PADD + kq * 4];
                o[0][c] += x0.x * w.x + x0.y * w.y + x0.z * w.z + x0.w * w.w;
                o[1][c] += x1.x * w.x + x1.y * w.y + x1.z * w.z + x1.w * w.w;
            }
        }
        #pragma unroll
        for (int r = 0; r < 2; r++) {
            int gr = base + r0 + r;
            if (gr < N_NODES) {
                #pragma unroll
                for (int c = 0; c < 3; c++)
                    out[gr * N_CLASS + cc0 + c] = o[r][c] + fc2b[cc0 + c];
            }
        }
    }
}

// ---------------- launch ----------------

extern "C" void kernel_launch(void* const* d_in, const int* in_sizes, int n_in,
                              void* d_out, int out_size, void* d_ws, size_t ws_size,
                              hipStream_t stream) {
    const float* x     = (const float*)d_in[0];
    const int*   ei    = (const int*)d_in[1];
    const float* c1_W1 = (const float*)d_in[2];
    const float* c1_b1 = (const float*)d_in[3];
    const float* c1_W2 = (const float*)d_in[4];
    const float* c1_b2 = (const float*)d_in[5];
    const float* c2_W1 = (const float*)d_in[6];
    const float* c2_b1 = (const float*)d_in[7];
    const float* c2_W2 = (const float*)d_in[8];
    const float* c2_b2 = (const float*)d_in[9];
    const float* bn1_g = (const float*)d_in[10];
    const float* bn1_b = (const float*)d_in[11];
    const float* bn1_m = (const float*)d_in[12];
    const float* bn1_v = (const float*)d_in[13];
    const float* bn2_g = (const float*)d_in[14];
    const float* bn2_b = (const float*)d_in[15];
    const float* bn2_m = (const float*)d_in[16];
    const float* bn2_v = (const float*)d_in[17];
    const float* fc1_W = (const float*)d_in[18];
    const float* fc1_b = (const float*)d_in[19];
    const float* fc2_W = (const float*)d_in[20];
    const float* fc2_b = (const float*)d_in[21];
    float* out = (float*)d_out;

    char* ws = (char*)d_ws;
    size_t o = 0;
    auto take = [&](size_t bytes) {
        void* p = ws + o;
        o = (o + bytes + 255) & ~(size_t)255;
        return p;
    };
    int*   sorted_src = (int*)take((size_t)N_EDGES * 4);
    int*   row_ptr    = (int*)take((size_t)(N_NODES + 1) * 4);
    int*   cursor     = (int*)take((size_t)N_NODES * 4);
    float* t1         = (float*)take((size_t)N_NODES * DIM * 4);  // aliased: t1 / u / t3 / u2
    float* t2         = (float*)take((size_t)N_NODES * DIM * 4);  // t2 / t4
    (void)ws_size; (void)in_sizes; (void)n_in; (void)out_size;

    const int EB = N_EDGES / 256;           // 12500
    const int NB64 = (N_NODES + 63) / 64;   // 1563
    const int NB4  = (N_NODES + 3) / 4;     // 25000

    hipMemsetAsync(row_ptr, 0, (size_t)(N_NODES + 1) * 4, stream);
    k_hist<<<EB, 256, 0, stream>>>(ei, row_ptr);
    k_scan<<<1, 1024, 0, stream>>>(row_ptr, cursor);
    k_scatter<<<EB, 256, 0, stream>>>(ei, cursor, sorted_src);

    k_g1<<<NB64, 256, 0, stream>>>(x, c1_W1, t1, t2);
    k_aggr<<<NB4, 256, 0, stream>>>(t1, t2, row_ptr, sorted_src, c1_b1, t1);
    k_chain1<<<NB64, 256, 0, stream>>>(t1, c1_W2, c1_b2, bn1_g, bn1_b, bn1_m, bn1_v,
                                       c2_W1, t1, t2);
    k_aggr<<<NB4, 256, 0, stream>>>(t1, t2, row_ptr, sorted_src, c2_b1, t1);
    k_chain2<<<NB64, 256, 0, stream>>>(t1, c2_W2, c2_b2, bn2_g, bn2_b, bn2_m, bn2_v,
                                       fc1_W, fc1_b, fc2_W, fc2_b, out);
}